// Round 3
// baseline (311.151 us; speedup 1.0000x reference)
//
#include <hip/hip_runtime.h>
#include <hip/hip_bf16.h>

#define Bdim 64
#define Tdim 2048
#define Fdim 256
#define TAIL 256      // truncated EMA window: 0.8^256 ~ 1e-25, far below fp32 noise
#define NCH 8
#define CHT 32        // TAIL / NCH
#define BM 64

typedef __bf16 bf16x8 __attribute__((ext_vector_type(8)));
typedef float f32x16 __attribute__((ext_vector_type(16)));
typedef unsigned short u16x8 __attribute__((ext_vector_type(8)));

__device__ __forceinline__ unsigned short bf16_rne(float f) {
  unsigned int u = __float_as_uint(f);
  u += 0x7FFFu + ((u >> 16) & 1u);
  return (unsigned short)(u >> 16);
}

__device__ __forceinline__ bf16x8 cvt8(float4 v0, float4 v1) {
  u16x8 w;
  w[0] = bf16_rne(v0.x); w[1] = bf16_rne(v0.y);
  w[2] = bf16_rne(v0.z); w[3] = bf16_rne(v0.w);
  w[4] = bf16_rne(v1.x); w[5] = bf16_rne(v1.y);
  w[6] = bf16_rne(v1.z); w[7] = bf16_rne(v1.w);
  return *(bf16x8*)&w;
}

// blocks 0..511: EMA partials part[c][b][f]; blocks 512..575: W [f][g] -> Wt [g][f] bf16
__global__ void prep(const float* __restrict__ x, const float* __restrict__ W,
                     unsigned short* __restrict__ Wt, float* __restrict__ part) {
  if (blockIdx.x >= 512) {
    int base = (blockIdx.x - 512) * 1024 + threadIdx.x * 4;
#pragma unroll
    for (int j = 0; j < 4; ++j) {
      int i = base + j;                 // i = g*256 + f
      int g = i >> 8, f = i & 255;
      Wt[i] = bf16_rne(W[f * Fdim + g]);
    }
    return;
  }
  int b = blockIdx.x & 63, c = blockIdx.x >> 6, f = threadIdx.x;
  int t0 = Tdim - TAIL + c * CHT;
  // w(t) = 0.2 * 0.8^(T-1-t); iterate upward multiplying by 1.25 (exact in fp32)
  float w = 0.2f * exp2f((float)(Tdim - 1 - t0) * -0.32192809488736235f);
  const float* xp = x + ((size_t)b * Tdim + t0) * Fdim + f;
  float s = 0.f;
#pragma unroll
  for (int j = 0; j < CHT; ++j) {
    s += w * xp[(size_t)j * Fdim];
    w *= 1.25f;
  }
  part[(c * Bdim + b) * Fdim + f] = s;
}

// Zero-LDS, zero-barrier streamer. Block = 4 waves; wave w owns output cols
// [w*64, w*64+64) for 64 rows. A-frags (m=lane&31, k=8*(lane>>5)+j — k-contiguous)
// load directly from row-major x as 2x float4 + in-register bf16 convert.
// B-frags load directly from Wt (L2-hot 128 KB). No LDS -> no barrier -> loads
// from all 16 k-steps pipeline freely; occupancy 4 waves/SIMD hides L2 latency.
__global__ __launch_bounds__(256, 4)
void gemm_fused(const float* __restrict__ x, const unsigned short* __restrict__ Wt,
                const float* __restrict__ bias, const float* __restrict__ part,
                float* __restrict__ out) {
  const int tid = threadIdx.x;
  const int blk = blockIdx.x;            // 0..2047
  const int b = blk >> 5;                // 32 row-tiles per batch
  const size_t row0 = (size_t)blk * BM;

  const int wave = tid >> 6;
  const int lane = tid & 63;
  const int lm = lane & 31;
  const int half = lane >> 5;
  const int n0 = wave * 64 + lm;
  const int n1 = n0 + 32;

  // lastref + bias for this lane's two output columns (L2-resident)
  float lb0 = bias[n0], lb1 = bias[n1];
#pragma unroll
  for (int c = 0; c < NCH; ++c) {
    lb0 += part[(c * Bdim + b) * Fdim + n0];
    lb1 += part[(c * Bdim + b) * Fdim + n1];
  }

  const float4* ax0 = (const float4*)&x[(row0 + lm) * Fdim + half * 8];
  const float4* ax1 = (const float4*)&x[(row0 + 32 + lm) * Fdim + half * 8];
  const u16x8* bw0 = (const u16x8*)&Wt[(size_t)n0 * Fdim + half * 8];
  const u16x8* bw1 = (const u16x8*)&Wt[(size_t)n1 * Fdim + half * 8];

  f32x16 acc[2][2] = {};                 // [m-subtile][n-subtile], 32x32 each

#pragma unroll
  for (int s = 0; s < 16; ++s) {
    // s*16 floats = s*4 float4s; s*16 ushorts = s*2 u16x8s
    float4 a0l = ax0[s * 4], a0h = ax0[s * 4 + 1];
    float4 a1l = ax1[s * 4], a1h = ax1[s * 4 + 1];
    u16x8 ub0 = bw0[s * 2];
    u16x8 ub1 = bw1[s * 2];
    bf16x8 a0 = cvt8(a0l, a0h);
    bf16x8 a1 = cvt8(a1l, a1h);
    bf16x8 b0 = *(bf16x8*)&ub0;
    bf16x8 b1 = *(bf16x8*)&ub1;
    acc[0][0] = __builtin_amdgcn_mfma_f32_32x32x16_bf16(a0, b0, acc[0][0], 0, 0, 0);
    acc[0][1] = __builtin_amdgcn_mfma_f32_32x32x16_bf16(a0, b1, acc[0][1], 0, 0, 0);
    acc[1][0] = __builtin_amdgcn_mfma_f32_32x32x16_bf16(a1, b0, acc[1][0], 0, 0, 0);
    acc[1][1] = __builtin_amdgcn_mfma_f32_32x32x16_bf16(a1, b1, acc[1][1], 0, 0, 0);
  }

  // epilogue: C/D layout col=lane&31, row=(r&3)+8*(r>>2)+4*(lane>>5)  [m74/m101]
  float* op = out + row0 * Fdim;
  const int rbase = 4 * half;
#pragma unroll
  for (int i = 0; i < 2; ++i) {
#pragma unroll
    for (int j = 0; j < 2; ++j) {
      const int n = (j == 0) ? n0 : n1;
      const float lb = (j == 0) ? lb0 : lb1;
#pragma unroll
      for (int r = 0; r < 16; ++r) {
        int rowi = i * 32 + (r & 3) + 8 * (r >> 2) + rbase;
        op[(size_t)rowi * Fdim + n] = acc[i][j][r] + lb;
      }
    }
  }
}

extern "C" void kernel_launch(void* const* d_in, const int* in_sizes, int n_in,
                              void* d_out, int out_size, void* d_ws, size_t ws_size,
                              hipStream_t stream) {
  const float* x = (const float*)d_in[0];
  const float* W = (const float*)d_in[1];
  const float* bias = (const float*)d_in[2];
  float* out = (float*)d_out;

  unsigned short* Wt = (unsigned short*)d_ws;                                   // 128 KB
  float* part = (float*)((char*)d_ws + Fdim * Fdim * sizeof(unsigned short));   // 512 KB

  prep<<<576, 256, 0, stream>>>(x, W, Wt, part);
  gemm_fused<<<(Bdim * Tdim) / BM, 256, 0, stream>>>(x, Wt, bias, part, out);
}